// Round 2
// baseline (113.875 us; speedup 1.0000x reference)
//
#include <hip/hip_runtime.h>
#include <hip/hip_bf16.h>

// RBF: out[n][o] = exp(-(||x_n - c_o|| / exp(ls_o))^2)
//    = exp(-(x_sq[n] - 2*dot(x_n,c_o) + c_sq[o]) * exp(-ls_o)^2)
// M=131072, K=128, O=512. Memory-bound (256 MiB output write dominates).
// bf16 MFMA for the cross term; fp32 row norms; fused exp epilogue.

typedef __attribute__((ext_vector_type(8))) short bf16x8;
typedef __attribute__((ext_vector_type(4))) float f32x4;

#define KDIM 128
#define ODIM 512
#define BM 64

// round-to-nearest-even fp32 -> bf16, two at a time, packed into one u32
__device__ __forceinline__ unsigned pack_bf2(float a, float b) {
    unsigned ua = __builtin_bit_cast(unsigned, a);
    unsigned ub = __builtin_bit_cast(unsigned, b);
    ua += 0x7fffu + ((ua >> 16) & 1u);
    ub += 0x7fffu + ((ub >> 16) & 1u);
    return (ua >> 16) | (ub & 0xffff0000u);
}

__global__ __launch_bounds__(256, 3) void rbf_mfma_kernel(
    const float* __restrict__ x,
    const float* __restrict__ centers,
    const float* __restrict__ log_sigmas,
    float* __restrict__ out)
{
    // LDS: A tile 64x128 bf16 (row stride 256B), B tile 128x128 bf16,
    // both XOR-swizzled by ((row&7)<<4) to kill the stride-256B bank conflict.
    __shared__ uint4 sA[BM * 16];    // 16 KiB
    __shared__ uint4 sB[128 * 16];   // 32 KiB
    __shared__ float sXsq[BM];
    __shared__ float sCsq[128];

    const int t  = threadIdx.x;       // 0..255 (4 waves)
    const int R0 = blockIdx.x * BM;   // first x-row of this block
    const int wv = t >> 6;            // wave id 0..3 -> owns rows wv*16..wv*16+15
    const int l  = t & 63;
    const int lr = l & 15;            // fragment row/col index
    const int lk = l >> 4;            // fragment k-group

    // ---- stage A: x tile fp32 -> bf16, with per-row sum of squares ----
    #pragma unroll
    for (int i = 0; i < 4; ++i) {
        int c    = i * 256 + t;       // 1024 chunks of 8 floats
        int row  = c >> 4;            // 0..63
        int col8 = c & 15;            // 8-float chunk within row
        const float4* gp = (const float4*)(x + (size_t)(R0 + row) * KDIM + col8 * 8);
        float4 v0 = gp[0], v1 = gp[1];
        float s = v0.x*v0.x + v0.y*v0.y + v0.z*v0.z + v0.w*v0.w
                + v1.x*v1.x + v1.y*v1.y + v1.z*v1.z + v1.w*v1.w;
        // 16 lanes share one row -> reduce within the 16-lane group
        s += __shfl_xor(s, 1); s += __shfl_xor(s, 2);
        s += __shfl_xor(s, 4); s += __shfl_xor(s, 8);
        if ((t & 15) == 0) sXsq[row] = s;
        uint4 w = { pack_bf2(v0.x, v0.y), pack_bf2(v0.z, v0.w),
                    pack_bf2(v1.x, v1.y), pack_bf2(v1.z, v1.w) };
        int byte = row * 256 + col8 * 16;
        byte ^= (row & 7) << 4;
        *(uint4*)((char*)sA + byte) = w;
    }

    bf16x8 afrag[4];  // this wave's 16 rows x K=128, hoisted across all chunks

    // ---- loop over 4 chunks of 128 output columns ----
    for (int c4 = 0; c4 < 4; ++c4) {
        // stage B: centers chunk fp32 -> bf16, with per-center sum of squares
        #pragma unroll
        for (int i = 0; i < 8; ++i) {
            int c    = i * 256 + t;   // 2048 chunks of 8 floats
            int row  = c >> 4;        // 0..127
            int col8 = c & 15;
            const float4* gp = (const float4*)(centers + (size_t)(c4 * 128 + row) * KDIM + col8 * 8);
            float4 v0 = gp[0], v1 = gp[1];
            float s = v0.x*v0.x + v0.y*v0.y + v0.z*v0.z + v0.w*v0.w
                    + v1.x*v1.x + v1.y*v1.y + v1.z*v1.z + v1.w*v1.w;
            s += __shfl_xor(s, 1); s += __shfl_xor(s, 2);
            s += __shfl_xor(s, 4); s += __shfl_xor(s, 8);
            if ((t & 15) == 0) sCsq[row] = s;
            uint4 w = { pack_bf2(v0.x, v0.y), pack_bf2(v0.z, v0.w),
                        pack_bf2(v1.x, v1.y), pack_bf2(v1.z, v1.w) };
            int byte = row * 256 + col8 * 16;
            byte ^= (row & 7) << 4;
            *(uint4*)((char*)sB + byte) = w;
        }
        __syncthreads();  // staging (A on first iter, B every iter) visible

        if (c4 == 0) {
            #pragma unroll
            for (int kk = 0; kk < 4; ++kk) {
                int row  = wv * 16 + lr;
                int byte = row * 256 + kk * 64 + lk * 16;
                byte ^= (row & 7) << 4;
                afrag[kk] = *(bf16x8*)((char*)sA + byte);
            }
        }

        // ---- MFMA: this wave's 16 rows x 128 cols of this chunk ----
        f32x4 acc[8];
        #pragma unroll
        for (int nb = 0; nb < 8; ++nb) acc[nb] = (f32x4){0.f, 0.f, 0.f, 0.f};
        #pragma unroll
        for (int nb = 0; nb < 8; ++nb) {
            #pragma unroll
            for (int kk = 0; kk < 4; ++kk) {
                int row  = nb * 16 + lr;
                int byte = row * 256 + kk * 64 + lk * 16;
                byte ^= (row & 7) << 4;
                bf16x8 b = *(const bf16x8*)((const char*)sB + byte);
                acc[nb] = __builtin_amdgcn_mfma_f32_16x16x32_bf16(afrag[kk], b, acc[nb], 0, 0, 0);
            }
        }

        // ---- epilogue: d2 -> exp, fused store ----
        #pragma unroll
        for (int nb = 0; nb < 8; ++nb) {
            int coll = nb * 16 + lr;          // local col 0..127
            int col  = c4 * 128 + coll;       // global col
            float cs  = sCsq[coll];
            float ls  = log_sigmas[col];
            float is  = __expf(-ls);
            float is2 = is * is;
            #pragma unroll
            for (int j = 0; j < 4; ++j) {
                int rl = wv * 16 + lk * 4 + j;  // C/D: row=(l>>4)*4+reg, col=l&15
                float d2 = sXsq[rl] - 2.0f * acc[nb][j] + cs;
                d2 = fmaxf(d2, 0.0f);
                out[(size_t)(R0 + rl) * ODIM + col] = __expf(-d2 * is2);
            }
        }
        __syncthreads();  // protect sB before next chunk's staging
    }
}

extern "C" void kernel_launch(void* const* d_in, const int* in_sizes, int n_in,
                              void* d_out, int out_size, void* d_ws, size_t ws_size,
                              hipStream_t stream) {
    const float* x          = (const float*)d_in[0];
    const float* centers    = (const float*)d_in[1];
    const float* log_sigmas = (const float*)d_in[2];
    float* out = (float*)d_out;

    const int n_rows = in_sizes[0] / KDIM;          // 131072
    const int grid   = n_rows / BM;                 // 2048 blocks
    rbf_mfma_kernel<<<grid, 256, 0, stream>>>(x, centers, log_sigmas, out);
}